// Round 4
// baseline (992.531 us; speedup 1.0000x reference)
//
#include <hip/hip_runtime.h>
#include <stdint.h>

// ConvTranspose2d-shaped op per jax.lax.conv_transpose(transpose_kernel=True,
// dimension_numbers=("NCHW","IOHW","NCHW"), VALID, stride 1):
//   out[co,oh,ow] = sum_{ci,kh,kw} x[ci,oh-kh,ow-kw] * w[co, ci, kh, kw]
// NOTE: contraction is over AXIS 1 of w[64,64,3,3]; output channel is AXIS 0.
// (jax's transpose_kernel swaps I/O then contracts — NOT torch's axis-0
//  contraction. r1-r3 bit-identical scramble proved the layout chain correct
//  and isolated this weight-axis transpose as the sole bug.)
// Implicit-GEMM bf16 MFMA 16x16x32; A/B/D layouts validated r1-r3:
//   A: m=lane&15, k=quad*8+j ; B: n=lane&15, k=quad*8+j ; D: row=4*quad+reg, col=lane&15.

typedef short s16x8 __attribute__((ext_vector_type(8)));
typedef float f32x4 __attribute__((ext_vector_type(4)));

#define HIN   1024
#define WIN   1024
#define OHT   1026
#define OWT   1026
#define TH    4     // output rows per tile
#define TW    32    // output cols per tile
#define LRN   6     // TH+2 staged input rows
#define LCN   34    // TW+2 staged input cols
#define ROWG  64    // grid.y
#define NTILE 257   // ceil(1026/4)

__device__ __forceinline__ short f2bf(float v) {
    return __builtin_bit_cast(short, (__bf16)v);
}

__global__ __launch_bounds__(256, 2)
void convt_mfma(const float* __restrict__ x, const float* __restrict__ w,
                float* __restrict__ out) {
    // LDS x tile: [lr][lc][ci] bf16, ci innermost; 16B chunk c stored at
    // (c ^ (lc&7)) so MFMA B-fragment reads are bank-conflict-free.
    __shared__ __align__(16) short lds[LRN * LCN * 64];

    const int tid  = threadIdx.x;
    const int wave = tid >> 6;
    const int lane = tid & 63;
    const int n    = lane & 15;   // MFMA col (pixel) / A-row (co) lane index
    const int quad = lane >> 4;   // 0..3

    const int ow0 = blockIdx.x * TW;

    // ---- Preload A fragments (weights), whole K=576 for this wave's 16 co ----
    // kk: tap=kk>>1 (kh*3+kw), ci=(kk&1)*32 + quad*8 + j
    // CORRECTED: w[co, ci, tap] = w[co*576 + ci*9 + tap]
    const int co_a = (wave << 4) + n;
    s16x8 afrag[18];
    #pragma unroll
    for (int kk = 0; kk < 18; ++kk) {
        const int tap = kk >> 1;
        const int cib = ((kk & 1) << 5) + (quad << 3);
        const float* wp = w + co_a * 576 + tap;
        #pragma unroll
        for (int j = 0; j < 8; ++j) {
            afrag[kk][j] = f2bf(wp[(cib + j) * 9]);
        }
    }

    for (int rt = blockIdx.y; rt < NTILE; rt += ROWG) {
        const int oh0 = rt * TH;

        // ---- Stage x tile fp32 -> bf16 into LDS ----
        for (int cell = tid; cell < 8 * LRN * LCN; cell += 256) {
            const int c   = cell / (LRN * LCN);
            const int rem = cell - c * (LRN * LCN);
            const int lr  = rem / LCN;
            const int lc  = rem - lr * LCN;
            const int ih  = oh0 - 2 + lr;
            const int iw  = ow0 - 2 + lc;
            const bool ok = ((unsigned)ih < (unsigned)HIN) && ((unsigned)iw < (unsigned)WIN);
            const long base = (long)(c << 3) * (HIN * WIN) + (long)ih * WIN + iw;
            s16x8 pv;
            #pragma unroll
            for (int j = 0; j < 8; ++j) {
                const float v = ok ? x[base + (long)j * (HIN * WIN)] : 0.0f;
                pv[j] = f2bf(v);
            }
            const int ch = c ^ (lc & 7);
            *(s16x8*)&lds[(lr * LCN + lc) * 64 + ch * 8] = pv;
        }
        __syncthreads();

        // ---- MFMA main loop ----
        f32x4 acc[TH][2];
        #pragma unroll
        for (int r = 0; r < TH; ++r)
            #pragma unroll
            for (int nt = 0; nt < 2; ++nt)
                acc[r][nt] = (f32x4){0.f, 0.f, 0.f, 0.f};

        #pragma unroll
        for (int kk = 0; kk < 18; ++kk) {
            const int tap = kk >> 1;
            const int kh  = tap / 3;
            const int kw  = tap - kh * 3;
            const int cq  = ((kk & 1) << 2) + quad;
            #pragma unroll
            for (int r = 0; r < TH; ++r) {
                const int lr = r + 2 - kh;
                #pragma unroll
                for (int nt = 0; nt < 2; ++nt) {
                    const int lc = nt * 16 + n + 2 - kw;
                    const int ch = cq ^ (lc & 7);
                    const s16x8 b = *(const s16x8*)&lds[(lr * LCN + lc) * 64 + ch * 8];
                    acc[r][nt] = __builtin_amdgcn_mfma_f32_16x16x32_bf16(
                        afrag[kk], b, acc[r][nt], 0, 0, 0);
                }
            }
        }
        __syncthreads();

        // ---- Store: D row(co)=4*quad+reg, col(pixel)=lane&15 ----
        #pragma unroll
        for (int r = 0; r < TH; ++r) {
            const int oh = oh0 + r;
            if (oh < OHT) {
                #pragma unroll
                for (int nt = 0; nt < 2; ++nt) {
                    const int ow = ow0 + nt * 16 + n;
                    if (ow < OWT) {
                        const int co = (wave << 4) + (quad << 2);
                        float* op = out + (long)co * (OHT * OWT) + (long)oh * OWT + ow;
                        #pragma unroll
                        for (int reg = 0; reg < 4; ++reg)
                            op[(long)reg * (OHT * OWT)] = acc[r][nt][reg];
                    }
                }
            }
        }
    }
}

extern "C" void kernel_launch(void* const* d_in, const int* in_sizes, int n_in,
                              void* d_out, int out_size, void* d_ws, size_t ws_size,
                              hipStream_t stream) {
    const int i_x = (in_sizes[0] > in_sizes[1]) ? 0 : 1;
    const float* x = (const float*)d_in[i_x];   // [64,1024,1024]
    const float* w = (const float*)d_in[1 - i_x]; // [64,64,3,3]
    float* out = (float*)d_out;                 // [64,1026,1026]

    dim3 grid((OWT + TW - 1) / TW, ROWG);       // 33 x 64
    dim3 block(256);
    convt_mfma<<<grid, block, 0, stream>>>(x, w, out);
}